// Round 4
// baseline (353.565 us; speedup 1.0000x reference)
//
#include <hip/hip_runtime.h>
#include <hip/hip_cooperative_groups.h>
#include <cmath>

namespace cg = cooperative_groups;

#define N_ROWS 2048
#define DIM 4096
#define ROW_STRIDE 8192   // features[:,0,:] -> row i at offset i*2*4096
#define NCLS 8
#define NY   32           // y-slices (64 rows each)
#define SLICE_WORDS (2*NCLS*DIM)   // 65536 floats per slice: [P(c,d)][L(c,d)]
#define NBLK 512

// ---- workspace float offsets (identical layout for mega + fallback) ----
#define OFF_LSE    0
#define OFF_DIAG   (N_ROWS)                      // 2048
#define OFF_PL     (2*N_ROWS)                    // 4096  (16 KiB -> float4 aligned)
#define OFF_SLICES (OFF_PL + SLICE_WORDS)        // 69632
#define OFF_SCAL   (OFF_SLICES + NY*SLICE_WORDS) // 2166784 floats = 8667136 B (8B aligned)
// scalar area: D[8] double, Spart[16] double, Apart[16] double, Ncnt[8] int

__device__ __forceinline__ float wred_sum(float v){
  #pragma unroll
  for(int o=32;o>0;o>>=1) v += __shfl_xor(v,o,64);
  return v;
}
__device__ __forceinline__ float wred_max(float v){
  #pragma unroll
  for(int o=32;o>0;o>>=1) v = fmaxf(v,__shfl_xor(v,o,64));
  return v;
}
__device__ __forceinline__ double wred_sum_d(double v){
  #pragma unroll
  for(int o=32;o>0;o>>=1) v += __shfl_xor(v,o,64);
  return v;
}

// =====================================================================
// MEGA: all phases in one cooperative kernel.
//  P1: row stats (lse, diag), 4 rows/block.
//  P2: per-column per-class P/L accumulation into private y-slices.
//  P3: blocks 0..255 reduce slices -> PLfinal; block 256 does per-class
//      diag sums (runs in parallel with the reduction).
//  P4: blocks 0..15 column partials (fp64) -> Spart/Apart.
//  P5: block 0 combines -> out.
// =====================================================================
__global__ __launch_bounds__(256,2) void mega(
    const float* __restrict__ feat, const int* __restrict__ labels,
    float* __restrict__ ws, float* __restrict__ out){
  cg::grid_group grid = cg::this_grid();
  const int b = blockIdx.x, t = threadIdx.x;
  const int wave = t>>6, lane = t&63;

  float* lse    = ws + OFF_LSE;
  float* diag   = ws + OFF_DIAG;
  float* PL     = ws + OFF_PL;       // [P 32768][L 32768]
  float* slices = ws + OFF_SLICES;
  double* Dsum  = (double*)(ws + OFF_SCAL);
  double* Spart = Dsum + 8;
  double* Apart = Spart + 16;
  int*    Ncnt  = (int*)(Apart + 16);

  __shared__ float  redf[8];
  __shared__ double sD[4][8];
  __shared__ int    sN[4][8];
  __shared__ double sS[4], sA[4];

  // ---------------- P1: row stats (k1 body, 4 rows sequentially) --------
  for(int rr=0; rr<4; rr++){
    const int row = b*4 + rr;
    const float4* x4 = (const float4*)(feat + (size_t)row * ROW_STRIDE);
    float4 v[4];
    #pragma unroll
    for(int k=0;k<4;k++) v[k] = x4[t + k*256];
    float m = -INFINITY;
    #pragma unroll
    for(int k=0;k<4;k++)
      m = fmaxf(m, fmaxf(fmaxf(v[k].x,v[k].y), fmaxf(v[k].z,v[k].w)));
    m = wred_max(m);
    if(lane==0) redf[wave] = m;
    __syncthreads();
    m = fmaxf(fmaxf(redf[0],redf[1]), fmaxf(redf[2],redf[3]));
    __syncthreads();
    float s = 0.f, t1 = 0.f;
    #pragma unroll
    for(int k=0;k<4;k++){
      float a=v[k].x-m, b2=v[k].y-m, c=v[k].z-m, d2=v[k].w-m;
      float ea=__expf(a), eb=__expf(b2), ec=__expf(c), ed=__expf(d2);
      s  += ea + eb + ec + ed;
      t1 += a*ea + b2*eb + c*ec + d2*ed;
    }
    s  = wred_sum(s);
    t1 = wred_sum(t1);
    if(lane==0){ redf[wave] = s; redf[4+wave] = t1; }
    __syncthreads();
    if(t==0){
      float S  = redf[0]+redf[1]+redf[2]+redf[3];
      float T1 = redf[4]+redf[5]+redf[6]+redf[7];
      float lg = __logf(S);
      lse[row]  = m + lg;
      diag[row] = T1/S - lg;
    }
    __syncthreads();   // redf reused next row
  }
  grid.sync();

  // ---------------- P2: column accumulation (k2 body) -------------------
  {
    const int x = b & 15, y = b >> 4;
    const int d = x * 256 + t;
    const int r0 = y * 64;
    float P0=0,P1=0,P2=0,P3=0,P4=0,P5=0,P6=0,P7=0;
    float L0=0,L1=0,L2=0,L3=0,L4=0,L5=0,L6=0,L7=0;
    const float* col = feat + (size_t)r0 * ROW_STRIDE + d;
    for(int ib=0; ib<4; ib++){
      float xs[16];
      #pragma unroll
      for(int j=0;j<16;j++)
        xs[j] = col[(size_t)(ib*16+j) * ROW_STRIDE];
      #pragma unroll
      for(int j=0;j<16;j++){
        const int r = r0 + ib*16 + j;
        float vv = xs[j] - lse[r];
        float e = __expf(vv);
        int lab = __builtin_amdgcn_readfirstlane(labels[r]);
        switch(lab){
          case 0: P0+=e; L0+=vv; break;
          case 1: P1+=e; L1+=vv; break;
          case 2: P2+=e; L2+=vv; break;
          case 3: P3+=e; L3+=vv; break;
          case 4: P4+=e; L4+=vv; break;
          case 5: P5+=e; L5+=vv; break;
          case 6: P6+=e; L6+=vv; break;
          default: P7+=e; L7+=vv; break;
        }
      }
    }
    float* slice = slices + (size_t)y * SLICE_WORDS;
    float* Ps = slice;
    float* Ls = slice + NCLS*DIM;
    Ps[0*DIM+d]=P0; Ls[0*DIM+d]=L0;
    Ps[1*DIM+d]=P1; Ls[1*DIM+d]=L1;
    Ps[2*DIM+d]=P2; Ls[2*DIM+d]=L2;
    Ps[3*DIM+d]=P3; Ls[3*DIM+d]=L3;
    Ps[4*DIM+d]=P4; Ls[4*DIM+d]=L4;
    Ps[5*DIM+d]=P5; Ls[5*DIM+d]=L5;
    Ps[6*DIM+d]=P6; Ls[6*DIM+d]=L6;
    Ps[7*DIM+d]=P7; Ls[7*DIM+d]=L7;
  }
  grid.sync();

  // ---------------- P3: slice reduction + (parallel) diag class sums ----
  if(b < 256){
    const int gid = b*256 + t;   // exactly covers [0, 65536)
    float s = 0.f;
    #pragma unroll 8
    for(int y=0;y<NY;y++)
      s += slices[(size_t)y * SLICE_WORDS + gid];
    PL[gid] = s;
  } else if(b == 256){
    double Dl[8]; int Nl[8];
    #pragma unroll
    for(int c=0;c<8;c++){ Dl[c]=0.0; Nl[c]=0; }
    for(int i=t;i<N_ROWS;i+=256){
      int lab = labels[i];
      double dg = (double)diag[i];
      #pragma unroll
      for(int c=0;c<8;c++){
        if(lab==c){ Dl[c]+=dg; Nl[c]++; }
      }
    }
    #pragma unroll
    for(int c=0;c<8;c++){
      #pragma unroll
      for(int o=32;o>0;o>>=1){
        Dl[c] += __shfl_xor(Dl[c],o,64);
        Nl[c] += __shfl_xor(Nl[c],o,64);
      }
    }
    if(lane==0){
      #pragma unroll
      for(int c=0;c<8;c++){ sD[wave][c]=Dl[c]; sN[wave][c]=Nl[c]; }
    }
    __syncthreads();
    if(t<8){
      Dsum[t] = sD[0][t]+sD[1][t]+sD[2][t]+sD[3][t];
      Ncnt[t] = sN[0][t]+sN[1][t]+sN[2][t]+sN[3][t];
    }
  }
  grid.sync();

  // ---------------- P4: column partials (16 blocks, fp64) ---------------
  if(b < 16){
    const int d = b*256 + t;
    double acc_same=0.0, ps=0.0, ls=0.0;
    #pragma unroll
    for(int c=0;c<8;c++){
      float p  = PL[c*DIM + d];
      float lq = PL[NCLS*DIM + c*DIM + d];
      acc_same += (double)p*(double)lq;
      ps += (double)p; ls += (double)lq;
    }
    double acc_all = ps*ls;
    acc_same = wred_sum_d(acc_same);
    acc_all  = wred_sum_d(acc_all);
    if(lane==0){ sS[wave]=acc_same; sA[wave]=acc_all; }
    __syncthreads();
    if(t==0){
      Spart[b] = sS[0]+sS[1]+sS[2]+sS[3];
      Apart[b] = sA[0]+sA[1]+sA[2]+sA[3];
    }
  }
  grid.sync();

  // ---------------- P5: combine ----------------------------------------
  if(b==0 && t==0){
    double S_same=0.0, S_all=0.0;
    #pragma unroll
    for(int i=0;i<16;i++){ S_same += Spart[i]; S_all += Apart[i]; }
    double same_num=0.0, diff_num=0.0;
    #pragma unroll
    for(int c=0;c<8;c++){
      same_num += (double)Ncnt[c]*Dsum[c];
      diff_num += (double)(N_ROWS - Ncnt[c])*Dsum[c];
    }
    same_num -= S_same;            // = same_sum * 2d
    diff_num -= (S_all - S_same);  // = diff_sum * 2d
    out[0] = (float)(same_num/diff_num);
  }
}

// =====================================================================
// Fallback path: the proven round-3 4-kernel pipeline (same ws layout).
// =====================================================================
__global__ __launch_bounds__(256) void k1_rowstats(
    const float* __restrict__ feat, float* __restrict__ lse,
    float* __restrict__ diag){
  const int t = threadIdx.x;
  const int row = blockIdx.x;
  const int wave = t>>6, lane = t&63;
  const float4* x4 = (const float4*)(feat + (size_t)row * ROW_STRIDE);
  float4 v[4];
  #pragma unroll
  for(int k=0;k<4;k++) v[k] = x4[t + k*256];
  __shared__ float red[8];
  float m = -INFINITY;
  #pragma unroll
  for(int k=0;k<4;k++)
    m = fmaxf(m, fmaxf(fmaxf(v[k].x,v[k].y), fmaxf(v[k].z,v[k].w)));
  m = wred_max(m);
  if(lane==0) red[wave] = m;
  __syncthreads();
  m = fmaxf(fmaxf(red[0],red[1]), fmaxf(red[2],red[3]));
  __syncthreads();
  float s = 0.f, t1 = 0.f;
  #pragma unroll
  for(int k=0;k<4;k++){
    float a=v[k].x-m, b=v[k].y-m, c=v[k].z-m, d2=v[k].w-m;
    float ea=__expf(a), eb=__expf(b), ec=__expf(c), ed=__expf(d2);
    s  += ea + eb + ec + ed;
    t1 += a*ea + b*eb + c*ec + d2*ed;
  }
  s  = wred_sum(s);
  t1 = wred_sum(t1);
  if(lane==0){ red[wave] = s; red[4+wave] = t1; }
  __syncthreads();
  if(t==0){
    float S  = red[0]+red[1]+red[2]+red[3];
    float T1 = red[4]+red[5]+red[6]+red[7];
    float lg = __logf(S);
    lse[row]  = m + lg;
    diag[row] = T1/S - lg;
  }
}

__global__ __launch_bounds__(256,2) void k2_accum(
    const float* __restrict__ feat, const float* __restrict__ lse,
    const int* __restrict__ labels,
    float* __restrict__ PLslices){
  const int d = blockIdx.x * 256 + threadIdx.x;
  const int y = blockIdx.y;
  const int r0 = y * 64;
  float P0=0,P1=0,P2=0,P3=0,P4=0,P5=0,P6=0,P7=0;
  float L0=0,L1=0,L2=0,L3=0,L4=0,L5=0,L6=0,L7=0;
  const float* col = feat + (size_t)r0 * ROW_STRIDE + d;
  for(int ib=0; ib<4; ib++){
    float xs[16];
    #pragma unroll
    for(int j=0;j<16;j++)
      xs[j] = col[(size_t)(ib*16+j) * ROW_STRIDE];
    #pragma unroll
    for(int j=0;j<16;j++){
      const int r = r0 + ib*16 + j;
      float v = xs[j] - lse[r];
      float e = __expf(v);
      int lab = __builtin_amdgcn_readfirstlane(labels[r]);
      switch(lab){
        case 0: P0+=e; L0+=v; break;
        case 1: P1+=e; L1+=v; break;
        case 2: P2+=e; L2+=v; break;
        case 3: P3+=e; L3+=v; break;
        case 4: P4+=e; L4+=v; break;
        case 5: P5+=e; L5+=v; break;
        case 6: P6+=e; L6+=v; break;
        default: P7+=e; L7+=v; break;
      }
    }
  }
  float* slice = PLslices + (size_t)y * SLICE_WORDS;
  float* Ps = slice;
  float* Ls = slice + NCLS*DIM;
  Ps[0*DIM+d]=P0; Ls[0*DIM+d]=L0;
  Ps[1*DIM+d]=P1; Ls[1*DIM+d]=L1;
  Ps[2*DIM+d]=P2; Ls[2*DIM+d]=L2;
  Ps[3*DIM+d]=P3; Ls[3*DIM+d]=L3;
  Ps[4*DIM+d]=P4; Ls[4*DIM+d]=L4;
  Ps[5*DIM+d]=P5; Ls[5*DIM+d]=L5;
  Ps[6*DIM+d]=P6; Ls[6*DIM+d]=L6;
  Ps[7*DIM+d]=P7; Ls[7*DIM+d]=L7;
}

__global__ __launch_bounds__(256) void k2b_reduce(
    const float* __restrict__ PLslices, float* __restrict__ PLfinal){
  const int gid = blockIdx.x * 256 + threadIdx.x;
  float s = 0.f;
  #pragma unroll 8
  for(int y=0;y<NY;y++)
    s += PLslices[(size_t)y * SLICE_WORDS + gid];
  PLfinal[gid] = s;
}

__global__ __launch_bounds__(1024) void k3_final(
    const float* __restrict__ diag, const int* __restrict__ labels,
    const float* __restrict__ Pbuf, const float* __restrict__ Lbuf,
    float* __restrict__ out){
  const int t = threadIdx.x;
  const int wave = t>>6, lane = t&63;
  __shared__ double sD[16][8];
  __shared__ int    sN[16][8];
  __shared__ double sS[16], sA[16];
  double Dl[8]; int Nl[8];
  #pragma unroll
  for(int c=0;c<8;c++){ Dl[c]=0.0; Nl[c]=0; }
  for(int i=t;i<N_ROWS;i+=1024){
    int lab = labels[i];
    double dg = (double)diag[i];
    #pragma unroll
    for(int c=0;c<8;c++){
      if(lab==c){ Dl[c]+=dg; Nl[c]++; }
    }
  }
  #pragma unroll
  for(int c=0;c<8;c++){
    #pragma unroll
    for(int o=32;o>0;o>>=1){
      Dl[c] += __shfl_xor(Dl[c],o,64);
      Nl[c] += __shfl_xor(Nl[c],o,64);
    }
  }
  if(lane==0){
    #pragma unroll
    for(int c=0;c<8;c++){ sD[wave][c]=Dl[c]; sN[wave][c]=Nl[c]; }
  }
  double acc_same=0.0, acc_all=0.0;
  {
    const int base = t*4;
    double ps0=0,ps1=0,ps2=0,ps3=0, ls0=0,ls1=0,ls2=0,ls3=0;
    #pragma unroll
    for(int c=0;c<8;c++){
      float4 p4 = *(const float4*)&Pbuf[c*DIM + base];
      float4 l4 = *(const float4*)&Lbuf[c*DIM + base];
      acc_same += (double)p4.x*(double)l4.x + (double)p4.y*(double)l4.y
                + (double)p4.z*(double)l4.z + (double)p4.w*(double)l4.w;
      ps0 += p4.x; ps1 += p4.y; ps2 += p4.z; ps3 += p4.w;
      ls0 += l4.x; ls1 += l4.y; ls2 += l4.z; ls3 += l4.w;
    }
    acc_all = ps0*ls0 + ps1*ls1 + ps2*ls2 + ps3*ls3;
  }
  #pragma unroll
  for(int o=32;o>0;o>>=1){
    acc_same += __shfl_xor(acc_same,o,64);
    acc_all  += __shfl_xor(acc_all,o,64);
  }
  if(lane==0){ sS[wave]=acc_same; sA[wave]=acc_all; }
  __syncthreads();
  if(t==0){
    double D[8]; int Ncnt2[8];
    #pragma unroll
    for(int c=0;c<8;c++){
      double d0=0.0; int n0=0;
      #pragma unroll
      for(int w=0;w<16;w++){ d0 += sD[w][c]; n0 += sN[w][c]; }
      D[c]=d0; Ncnt2[c]=n0;
    }
    double S_same=0.0, S_all=0.0;
    #pragma unroll
    for(int w=0;w<16;w++){ S_same += sS[w]; S_all += sA[w]; }
    double same_num=0.0, diff_num=0.0;
    #pragma unroll
    for(int c=0;c<8;c++){
      same_num += (double)Ncnt2[c]*D[c];
      diff_num += (double)(N_ROWS - Ncnt2[c])*D[c];
    }
    same_num -= S_same;
    diff_num -= (S_all - S_same);
    out[0] = (float)(same_num/diff_num);
  }
}

extern "C" void kernel_launch(void* const* d_in, const int* in_sizes, int n_in,
                              void* d_out, int out_size, void* d_ws, size_t ws_size,
                              hipStream_t stream){
  const float* feat   = (const float*)d_in[0];
  const int*   labels = (const int*)d_in[1];
  float* out = (float*)d_out;
  float* ws  = (float*)d_ws;

  void* args[] = { (void*)&feat, (void*)&labels, (void*)&ws, (void*)&out };
  hipError_t err = hipLaunchCooperativeKernel(
      (const void*)mega, dim3(NBLK), dim3(256), args, 0, stream);

  if(err != hipSuccess){
    // Fallback: proven 4-kernel pipeline (same ws layout).
    float* lse      = ws + OFF_LSE;
    float* diag     = ws + OFF_DIAG;
    float* PLfinal  = ws + OFF_PL;
    float* PLslices = ws + OFF_SLICES;
    k1_rowstats<<<N_ROWS, 256, 0, stream>>>(feat, lse, diag);
    k2_accum<<<dim3(DIM/256, NY), 256, 0, stream>>>(feat, lse, labels, PLslices);
    k2b_reduce<<<SLICE_WORDS/256, 256, 0, stream>>>(PLslices, PLfinal);
    k3_final<<<1, 1024, 0, stream>>>(diag, labels, PLfinal, PLfinal + NCLS*DIM, out);
  }
}

// Round 5
// 119.100 us; speedup vs baseline: 2.9686x; 2.9686x over previous
//
#include <hip/hip_runtime.h>
#include <cmath>

#define N_ROWS 2048
#define DIM 4096
#define ROW_STRIDE 8192   // features[:,0,:] -> row i at offset i*2*4096
#define NCLS 8
#define NY   32           // y-slices (64 rows each)
#define SLICE_WORDS (2*NCLS*DIM)   // 65536 floats per slice: [P(c,d)][L(c,d)]
#define K2C_BLOCKS 128

// ---- workspace float offsets ----
#define OFF_LSE    0
#define OFF_DIAG   (N_ROWS)                       // 2048
#define OFF_SLICES (2*N_ROWS)                     // 4096
#define OFF_SCAL   (OFF_SLICES + NY*SLICE_WORDS)  // 2101248 floats (8B-aligned byte off)
// scalar area: scal[2] double (Ssame, Sall), then count (uint)

__device__ __forceinline__ float wred_sum(float v){
  #pragma unroll
  for(int o=32;o>0;o>>=1) v += __shfl_xor(v,o,64);
  return v;
}
__device__ __forceinline__ float wred_max(float v){
  #pragma unroll
  for(int o=32;o>0;o>>=1) v = fmaxf(v,__shfl_xor(v,o,64));
  return v;
}

// One block per row: lse[row], diag[row] via fused pass.
// Block 0 also zeroes the fp64 accumulators + completion counter
// (stream order guarantees visibility to k2c).
__global__ __launch_bounds__(256) void k1_rowstats(
    const float* __restrict__ feat, float* __restrict__ lse,
    float* __restrict__ diag, double* __restrict__ scal){
  const int t = threadIdx.x;
  const int row = blockIdx.x;
  const int wave = t>>6, lane = t&63;
  if(row==0 && t==0){
    scal[0]=0.0; scal[1]=0.0;
    ((unsigned int*)(scal+2))[0] = 0u;
  }
  const float4* x4 = (const float4*)(feat + (size_t)row * ROW_STRIDE);
  float4 v[4];
  #pragma unroll
  for(int k=0;k<4;k++) v[k] = x4[t + k*256];

  __shared__ float red[8];
  float m = -INFINITY;
  #pragma unroll
  for(int k=0;k<4;k++)
    m = fmaxf(m, fmaxf(fmaxf(v[k].x,v[k].y), fmaxf(v[k].z,v[k].w)));
  m = wred_max(m);
  if(lane==0) red[wave] = m;
  __syncthreads();
  m = fmaxf(fmaxf(red[0],red[1]), fmaxf(red[2],red[3]));
  __syncthreads();
  float s = 0.f, t1 = 0.f;
  #pragma unroll
  for(int k=0;k<4;k++){
    float a=v[k].x-m, b=v[k].y-m, c=v[k].z-m, d2=v[k].w-m;
    float ea=__expf(a), eb=__expf(b), ec=__expf(c), ed=__expf(d2);
    s  += ea + eb + ec + ed;
    t1 += a*ea + b*eb + c*ec + d2*ed;
  }
  s  = wred_sum(s);
  t1 = wred_sum(t1);
  if(lane==0){ red[wave] = s; red[4+wave] = t1; }
  __syncthreads();
  if(t==0){
    float S  = red[0]+red[1]+red[2]+red[3];
    float T1 = red[4]+red[5]+red[6]+red[7];
    float lg = __logf(S);
    lse[row]  = m + lg;
    diag[row] = T1/S - lg;
  }
}

// grid (16, NY): thread owns column d of a 64-row chunk; 4 batches of 16
// branch-free loads; per-class register accumulation; plain coalesced
// stores to this y's private slice (zero atomics, zero init needed).
__global__ __launch_bounds__(256,2) void k2_accum(
    const float* __restrict__ feat, const float* __restrict__ lse,
    const int* __restrict__ labels,
    float* __restrict__ PLslices){
  const int d = blockIdx.x * 256 + threadIdx.x;
  const int y = blockIdx.y;
  const int r0 = y * 64;
  float P0=0,P1=0,P2=0,P3=0,P4=0,P5=0,P6=0,P7=0;
  float L0=0,L1=0,L2=0,L3=0,L4=0,L5=0,L6=0,L7=0;
  const float* col = feat + (size_t)r0 * ROW_STRIDE + d;
  for(int ib=0; ib<4; ib++){
    float xs[16];
    #pragma unroll
    for(int j=0;j<16;j++)
      xs[j] = col[(size_t)(ib*16+j) * ROW_STRIDE];
    #pragma unroll
    for(int j=0;j<16;j++){
      const int r = r0 + ib*16 + j;
      float v = xs[j] - lse[r];
      float e = __expf(v);
      int lab = __builtin_amdgcn_readfirstlane(labels[r]);
      switch(lab){
        case 0: P0+=e; L0+=v; break;
        case 1: P1+=e; L1+=v; break;
        case 2: P2+=e; L2+=v; break;
        case 3: P3+=e; L3+=v; break;
        case 4: P4+=e; L4+=v; break;
        case 5: P5+=e; L5+=v; break;
        case 6: P6+=e; L6+=v; break;
        default: P7+=e; L7+=v; break;
      }
    }
  }
  float* slice = PLslices + (size_t)y * SLICE_WORDS;
  float* Ps = slice;
  float* Ls = slice + NCLS*DIM;
  Ps[0*DIM+d]=P0; Ls[0*DIM+d]=L0;
  Ps[1*DIM+d]=P1; Ls[1*DIM+d]=L1;
  Ps[2*DIM+d]=P2; Ls[2*DIM+d]=L2;
  Ps[3*DIM+d]=P3; Ls[3*DIM+d]=L3;
  Ps[4*DIM+d]=P4; Ls[4*DIM+d]=L4;
  Ps[5*DIM+d]=P5; Ls[5*DIM+d]=L5;
  Ps[6*DIM+d]=P6; Ls[6*DIM+d]=L6;
  Ps[7*DIM+d]=P7; Ls[7*DIM+d]=L7;
}

// 128 blocks x 256 threads. Thread = (class c = t>>5, column d = b*32 + (t&31)).
// Sums its P and L words over the NY slices (old k2b), computes fp64
// P*L and per-column (sum_c P)(sum_c L) partials (old k3 column pass),
// block-reduces, 2 fp64 atomicAdds. Fence-counter: the LAST block to
// finish runs the diag/label class sums + final combine and writes out.
__global__ __launch_bounds__(256) void k2c_dot(
    const float* __restrict__ PLslices,
    const float* __restrict__ diag, const int* __restrict__ labels,
    double* __restrict__ scal, float* __restrict__ out){
  const int b = blockIdx.x, t = threadIdx.x;
  const int wave = t>>6, lane = t&63;
  const int c = t>>5;            // 0..7
  const int j = t&31;            // 0..31
  const int d = b*32 + j;        // column 0..4095
  unsigned int* count = (unsigned int*)(scal+2);

  // ---- y-reduction of this (c,d) pair ----
  float Pf=0.f, Lf=0.f;
  const float* basep = PLslices + c*DIM + d;
  const float* basel = basep + NCLS*DIM;
  #pragma unroll 8
  for(int y=0;y<NY;y++){
    Pf += basep[(size_t)y*SLICE_WORDS];
    Lf += basel[(size_t)y*SLICE_WORDS];
  }
  double acc_same = (double)Pf * (double)Lf;

  // ---- column sums across the 8 classes via LDS ----
  __shared__ float sPf[8][32], sLf[8][32];
  __shared__ double sS[4];
  sPf[c][j]=Pf; sLf[c][j]=Lf;
  __syncthreads();
  double acc_all = 0.0;
  if(t < 32){
    double ps=0.0, ls=0.0;
    #pragma unroll
    for(int cc=0;cc<8;cc++){ ps += (double)sPf[cc][t]; ls += (double)sLf[cc][t]; }
    acc_all = ps*ls;
  }
  // reduce acc_same over all 256 threads
  #pragma unroll
  for(int o=32;o>0;o>>=1) acc_same += __shfl_xor(acc_same,o,64);
  if(lane==0) sS[wave]=acc_same;
  // reduce acc_all over lanes 0..31 of wave 0 (xor<32 stays in-half)
  #pragma unroll
  for(int o=16;o>0;o>>=1) acc_all += __shfl_xor(acc_all,o,64);
  __syncthreads();
  if(t==0){
    atomicAdd(&scal[0], sS[0]+sS[1]+sS[2]+sS[3]);  // S_same partial
    atomicAdd(&scal[1], acc_all);                   // S_all partial
    __threadfence();                                // release before count
  }
  __syncthreads();

  // ---- fence-counter: last block finalizes ----
  __shared__ unsigned int is_last;
  if(t==0) is_last = (atomicAdd(count, 1u) == K2C_BLOCKS-1) ? 1u : 0u;
  __syncthreads();
  if(!is_last) return;

  // diag class sums + counts (256 threads, 8 iters)
  __shared__ double sD[4][8];
  __shared__ int    sN[4][8];
  double Dl[8]; int Nl[8];
  #pragma unroll
  for(int cc=0;cc<8;cc++){ Dl[cc]=0.0; Nl[cc]=0; }
  for(int i=t;i<N_ROWS;i+=256){
    int lab = labels[i];
    double dg = (double)diag[i];
    #pragma unroll
    for(int cc=0;cc<8;cc++){
      if(lab==cc){ Dl[cc]+=dg; Nl[cc]++; }
    }
  }
  #pragma unroll
  for(int cc=0;cc<8;cc++){
    #pragma unroll
    for(int o=32;o>0;o>>=1){
      Dl[cc] += __shfl_xor(Dl[cc],o,64);
      Nl[cc] += __shfl_xor(Nl[cc],o,64);
    }
  }
  if(lane==0){
    #pragma unroll
    for(int cc=0;cc<8;cc++){ sD[wave][cc]=Dl[cc]; sN[wave][cc]=Nl[cc]; }
  }
  __syncthreads();
  if(t==0){
    // atomic read-back (coherent across XCDs)
    double S_same = atomicAdd(&scal[0], 0.0);
    double S_all  = atomicAdd(&scal[1], 0.0);
    double same_num=0.0, diff_num=0.0;
    #pragma unroll
    for(int cc=0;cc<8;cc++){
      double Dc = sD[0][cc]+sD[1][cc]+sD[2][cc]+sD[3][cc];
      int    nc = sN[0][cc]+sN[1][cc]+sN[2][cc]+sN[3][cc];
      same_num += (double)nc*Dc;
      diff_num += (double)(N_ROWS - nc)*Dc;
    }
    same_num -= S_same;            // = same_sum * 2d
    diff_num -= (S_all - S_same);  // = diff_sum * 2d
    out[0] = (float)(same_num/diff_num);
  }
}

extern "C" void kernel_launch(void* const* d_in, const int* in_sizes, int n_in,
                              void* d_out, int out_size, void* d_ws, size_t ws_size,
                              hipStream_t stream){
  const float* feat   = (const float*)d_in[0];
  const int*   labels = (const int*)d_in[1];
  float* out = (float*)d_out;
  float* ws  = (float*)d_ws;
  float*  lse      = ws + OFF_LSE;
  float*  diag     = ws + OFF_DIAG;
  float*  PLslices = ws + OFF_SLICES;
  double* scal     = (double*)(ws + OFF_SCAL);

  k1_rowstats<<<N_ROWS, 256, 0, stream>>>(feat, lse, diag, scal);
  k2_accum<<<dim3(DIM/256, NY), 256, 0, stream>>>(feat, lse, labels, PLslices);
  k2c_dot<<<K2C_BLOCKS, 256, 0, stream>>>(PLslices, diag, labels, scal, out);
}